// Round 19
// baseline (309.430 us; speedup 1.0000x reference)
//
#include <hip/hip_runtime.h>

// MoE forward, MI355X — TERMINAL configuration (R17, 305.07us, best measured).
// fp32 router/dispatch (exact top-k), bf16 MFMA grouped GEMMs (9 groups),
// zero-elimination via shared-store split, fp32-atomic expert combine.
//
// Session ledger of validated decisions:
//  - GEMM core: m97-family 128x128, BK=64, 4 waves, single-buffer, 4 blocks/CU
//    (launch_bounds(256,4)); XOR chunk-swizzle (0 bank conflicts); bijective
//    XCD remap + 4-row-tile chunks (FETCH = unique bytes). 131us -> 111us
//    after zero-stream removal. Verified 12 runs.
//  - REFUTED this session: >4 waves/EU (R9: VGPR cap 512/waves -> acc spill,
//    3.3GB scratch); intra-block dbuf (R14: -16%, m99/m100 generalize);
//    depth-3 counted vmcnt (R5: +11% only); fine-phase interleave (R6/R7:
//    -15..-40%, m201 ledger not reproducible from prose); mega-fusion
//    (R11/R12: -15us, max-LDS-over-branches + codegen); 256^2/rect tiles
//    (R3/R7: neutral-to-worse at this structure's residency).
//  - Overhead at floor: tconv 1 launch (vector stores), router+convx fused,
//    dispatch+stats+aux fused, zero eliminated (GEMM2a plain-stores y).
// Not a hardware roofline (MfmaUtil ~20%): the gap is the m201-class
// schedule, unreproduced here and flagged OPEN in the source environment.

#define NTOK 8192
#define DDIM 1024
#define HDIM 1408
#define CAP  2560
#define NROWS (NTOK + 8*CAP)   // 28672 GEMM rows: [0,8192) shared, then 8*2560 expert slots
#define YN   8388608           // NTOK*DDIM

typedef __bf16 bf16x8 __attribute__((ext_vector_type(8)));
typedef float  f32x4  __attribute__((ext_vector_type(4)));

typedef __attribute__((address_space(1))) void gvoid_t;
typedef __attribute__((address_space(3))) void svoid_t;

static __device__ __forceinline__ void load_lds16(const void* g, void* l) {
  // 16B per lane, LDS dest = wave-uniform base + lane*16 (linear)
  __builtin_amdgcn_global_load_lds((gvoid_t*)g, (svoid_t*)l, 16, 0, 0);
}

// ------- transpose+convert v3: one launch for all 4 weight tensors -------
__global__ __launch_bounds__(256) void tconv3_kernel(
    const float* __restrict__ wfc, __bf16* __restrict__ B1,
    const float* __restrict__ wsfc,
    const float* __restrict__ wproj, __bf16* __restrict__ B2,
    const float* __restrict__ wsproj) {
  __shared__ float t[64][33];
  int z = blockIdx.z, tid = threadIdx.x;
  const float* ip;
  __bf16* op;
  int R, C;
  if (z < 9) {
    if (blockIdx.y >= 16) return;          // B1 geometry: 44 x 16
    R = 1024; C = 1408;
    ip = (z < 8) ? wfc + (size_t)z * R * C : wsfc;
    op = (z < 8) ? B1 + (size_t)z * (size_t)C * R : B1 + (size_t)8 * (size_t)C * R;
  } else {
    if (blockIdx.x >= 32) return;          // B2 geometry: 32 x 22
    R = 1408; C = 1024;
    int e = z - 9;
    ip = (e < 8) ? wproj + (size_t)e * R * C : wsproj;
    op = (e < 8) ? B2 + (size_t)e * (size_t)C * R : B2 + (size_t)8 * (size_t)C * R;
  }
  int c0 = blockIdx.x * 32, r0 = blockIdx.y * 64;
  int tx = tid & 31, ty = tid >> 5;          // read: 8 rows/pass, 128B/row coalesced
#pragma unroll
  for (int k = 0; k < 8; ++k)
    t[ty + k * 8][tx] = ip[(size_t)(r0 + ty + k * 8) * C + c0 + tx];
  __syncthreads();
  int cl = tid >> 3, rq = (tid & 7) * 8;     // write: one bf16x8 (16B) per thread
  bf16x8 o;                                  // LDS bank = (8q+j+p)%32 -> 2-way (free)
#pragma unroll
  for (int j = 0; j < 8; ++j) o[j] = (__bf16)t[rq + j][cl];
  *(bf16x8*)(op + (size_t)(c0 + cl) * R + r0 + rq) = o;
}

// ------- router (+ fused x->bf16 convert): fp32 logits, softmax, top-2, renorm -------
__global__ __launch_bounds__(256) void router_kernel(
    const float* __restrict__ x, const float* __restrict__ rw,
    __bf16* __restrict__ xbf,
    int2* __restrict__ e01, float2* __restrict__ p01,
    int* __restrict__ tok_row, float* __restrict__ scale_row,
    float* __restrict__ psum_part, int* __restrict__ fcnt_part) {
  __shared__ float rwl[8 * 1024];
  __shared__ float ps[8];
  __shared__ int fc[8];
  int tid = threadIdx.x;
  if (tid < 8) { ps[tid] = 0.f; fc[tid] = 0; }
  float4* rl4 = (float4*)rwl;
  const float4* rg4 = (const float4*)rw;
#pragma unroll
  for (int j = 0; j < 8; ++j) rl4[tid + 256 * j] = rg4[tid + 256 * j];
  __syncthreads();
  int lane = tid & 63, wid = tid >> 6;
  for (int it = 0; it < 8; ++it) {
    int t = blockIdx.x * 32 + wid * 8 + it;
    const float4* xt = (const float4*)(x + (size_t)t * DDIM);
    float a[8];
#pragma unroll
    for (int e = 0; e < 8; ++e) a[e] = 0.f;
    float4 v[4];
#pragma unroll
    for (int jj = 0; jj < 4; ++jj) {
      v[jj] = xt[lane * 4 + jj];
#pragma unroll
      for (int e = 0; e < 8; ++e) {
        float4 w = rl4[e * 256 + lane * 4 + jj];
        a[e] += v[jj].x * w.x + v[jj].y * w.y + v[jj].z * w.z + v[jj].w * w.w;
      }
    }
    {
      bf16x8 o0, o1;
#pragma unroll
      for (int jj = 0; jj < 2; ++jj) {
        o0[jj * 4 + 0] = (__bf16)v[jj].x; o0[jj * 4 + 1] = (__bf16)v[jj].y;
        o0[jj * 4 + 2] = (__bf16)v[jj].z; o0[jj * 4 + 3] = (__bf16)v[jj].w;
        o1[jj * 4 + 0] = (__bf16)v[jj + 2].x; o1[jj * 4 + 1] = (__bf16)v[jj + 2].y;
        o1[jj * 4 + 2] = (__bf16)v[jj + 2].z; o1[jj * 4 + 3] = (__bf16)v[jj + 2].w;
      }
      __bf16* xo = xbf + (size_t)t * DDIM + lane * 16;
      *(bf16x8*)xo = o0;
      *(bf16x8*)(xo + 8) = o1;
    }
#pragma unroll
    for (int off = 32; off >= 1; off >>= 1)
#pragma unroll
      for (int e = 0; e < 8; ++e) a[e] += __shfl_xor(a[e], off);
    if (lane == 0) {
      int am = 0; float m = a[0];
      for (int e = 1; e < 8; ++e) if (a[e] > m) { m = a[e]; am = e; }
      float s = 0.f, ex[8];
      for (int e = 0; e < 8; ++e) { ex[e] = expf(a[e] - m); s += ex[e]; }
      float inv = 1.f / s;
      int am2 = -1; float m2 = -3.4e38f;
      for (int e = 0; e < 8; ++e) if (e != am && a[e] > m2) { m2 = a[e]; am2 = e; }
      float p0 = ex[am] * inv, p1 = ex[am2] * inv;
      float rn = 1.f / (p0 + p1 + 1e-9f);
      e01[t] = make_int2(am, am2);
      p01[t] = make_float2(p0 * rn, p1 * rn);
      tok_row[t] = t;            // shared-group rows: identity gather, weight 1
      scale_row[t] = 1.f;
      atomicAdd(&fc[am], 1);
      for (int e = 0; e < 8; ++e) atomicAdd(&ps[e], ex[e] * inv);
    }
  }
  __syncthreads();
  if (tid < 8) { psum_part[blockIdx.x * 8 + tid] = ps[tid]; fcnt_part[blockIdx.x * 8 + tid] = fc[tid]; }
}

// ------- dispatch (+stat reduce +aux): stable rank within expert, capacity drop -------
__global__ __launch_bounds__(256) void dispatch_kernel(
    const int2* __restrict__ e01, const float2* __restrict__ p01,
    int* __restrict__ tok_row, float* __restrict__ scale_row, int* __restrict__ counts,
    const float* __restrict__ psum_part, const int* __restrict__ fcnt_part,
    float* __restrict__ aux_out) {
  __shared__ int lcnt[256][8];
  __shared__ float wps[4][8];
  __shared__ int wfcs[4][8];
  __shared__ float aps[8];
  __shared__ int afc[8];
  int tid = threadIdx.x, lane = tid & 63, w = tid >> 6;
  float s[8]; int c[8];
#pragma unroll
  for (int e = 0; e < 8; ++e) { s[e] = psum_part[tid * 8 + e]; c[e] = fcnt_part[tid * 8 + e]; }
#pragma unroll
  for (int off = 32; off >= 1; off >>= 1)
#pragma unroll
    for (int e = 0; e < 8; ++e) { s[e] += __shfl_xor(s[e], off); c[e] += __shfl_xor(c[e], off); }
  if (lane == 0) {
#pragma unroll
    for (int e = 0; e < 8; ++e) { wps[w][e] = s[e]; wfcs[w][e] = c[e]; }
  }
  int my[8];
#pragma unroll
  for (int e = 0; e < 8; ++e) my[e] = 0;
  int base = tid * 64;  // 256 threads * 64 entries = 16384 = N*K, contiguous => stable
  for (int j = 0; j < 64; ++j) {
    int ent = base + j; int t = ent >> 1;
    int2 ee = e01[t];
    int ex = (ent & 1) ? ee.y : ee.x;
    my[ex]++;
  }
#pragma unroll
  for (int e = 0; e < 8; ++e) lcnt[tid][e] = my[e];
  __syncthreads();
  if (tid < 8) {
    aps[tid] = wps[0][tid] + wps[1][tid] + wps[2][tid] + wps[3][tid];
    afc[tid] = wfcs[0][tid] + wfcs[1][tid] + wfcs[2][tid] + wfcs[3][tid];
    int run = 0;
    for (int i = 0; i < 256; ++i) { int cc = lcnt[i][tid]; lcnt[i][tid] = run; run += cc; }
    counts[tid] = run < CAP ? run : CAP;
  }
  __syncthreads();
  int offs[8];
#pragma unroll
  for (int e = 0; e < 8; ++e) offs[e] = lcnt[tid][e];
  for (int j = 0; j < 64; ++j) {
    int ent = base + j; int t = ent >> 1; int k = ent & 1;
    int2 ee = e01[t];
    int ex = k ? ee.y : ee.x;
    float pr = k ? p01[t].y : p01[t].x;
    int pos = offs[ex]++;
    if (pos < CAP) {
      int row = NTOK + ex * CAP + pos;
      tok_row[row] = t;
      scale_row[row] = pr;
    }
  }
  if (tid == 0) {
    float t = 0.f;
    for (int e = 0; e < 8; ++e) t += ((float)afc[e] / 8192.f) * (aps[e] / 8192.f);
    *aux_out = 0.08f * t;  // AUX_COEF * E = 0.01 * 8
  }
}

// ---------------- grouped GEMM, 128x128 tile, BK=64, 4 waves, single-buffer (m97 structure) ----------------
// RANGE: 0 = shared+expert tiles (GEMM1), 2 = expert-only (GEMM2b).
// EPI: 1 = H-store bf16(relu^2); 2 = atomicAdd(y, v*scale).
template <int KD, int NDT, bool GATHER, int EPI, int RANGE>
__global__ __launch_bounds__(256, 4) void gemm_kernel(
    const __bf16* __restrict__ A, const __bf16* __restrict__ B,
    __bf16* __restrict__ Hout, float* __restrict__ Yout,
    const int* __restrict__ counts, const int* __restrict__ tok_row,
    const float* __restrict__ scale_row) {
  constexpr int NCT = NDT / 128;
  constexpr int SH = NTOK / 128;   // 64 shared row-tiles
  constexpr int ET = CAP / 128;    // 20 expert row-tiles (worst case)
  int nwg = gridDim.x;
  int lin = (blockIdx.x & 7) * (nwg >> 3) + (blockIdx.x >> 3);
  int rem = lin % (4 * NCT);
  int rt = (lin / (4 * NCT)) * 4 + (rem & 3);
  int ct = rem >> 2;

  int g, i0, rowbase;
  if (RANGE == 2) { g = rt / ET; i0 = (rt % ET) << 7; rowbase = NTOK + g * CAP; }
  else {
    if (rt < SH) { g = 8; rowbase = 0; i0 = rt << 7; }
    else { int r = rt - SH; g = r / ET; i0 = (r % ET) << 7; rowbase = NTOK + g * CAP; }
  }
  int cnt = (g == 8) ? NTOK : counts[g];
  if (i0 >= cnt) return;  // uniform early-exit

  __shared__ __align__(16) __bf16 As[128 * 64];   // 16 KB
  __shared__ __align__(16) __bf16 Bs[128 * 64];   // 16 KB
  __shared__ int   toksL[128];
  __shared__ float sclL[128];

  int tid = threadIdx.x, lane = tid & 63, wid = tid >> 6;

  if (tid < 128) {
    int i = i0 + tid; if (i > cnt - 1) i = cnt - 1;  // pad rows duplicate last valid
    toksL[tid] = tok_row[rowbase + i];
    if (EPI == 2) sclL[tid] = scale_row[rowbase + i];
  }
  __syncthreads();

  int rsub = lane >> 3, csub = lane & 7;
  int csw = (csub ^ rsub) * 16;
  const char* aP[4];
  const char* bP[4];
  const char* Bg = (const char*)B + (size_t)g * NDT * KD * 2;
#pragma unroll
  for (int t = 0; t < 4; ++t) {
    int ia = wid * 32 + t * 8 + rsub;
    size_t arow = GATHER ? (size_t)toksL[ia] : (size_t)(rowbase + i0 + ia);
    aP[t] = (const char*)A + arow * (size_t)(KD * 2) + csw;
    int ib = ct * 128 + wid * 32 + t * 8 + rsub;
    bP[t] = Bg + (size_t)ib * (KD * 2) + csw;
  }

  f32x4 acc[4][4];
#pragma unroll
  for (int m2 = 0; m2 < 4; ++m2)
#pragma unroll
    for (int n2 = 0; n2 < 4; ++n2) acc[m2][n2] = f32x4{0.f, 0.f, 0.f, 0.f};

  int wr = wid >> 1, wc = wid & 1;
  int rA[4], rB[4], cS[2];
#pragma unroll
  for (int m2 = 0; m2 < 4; ++m2) rA[m2] = (wr * 64 + m2 * 16 + (lane & 15)) * 64;
#pragma unroll
  for (int n2 = 0; n2 < 4; ++n2) rB[n2] = (wc * 64 + n2 * 16 + (lane & 15)) * 64;
#pragma unroll
  for (int kk = 0; kk < 2; ++kk) cS[kk] = ((kk * 4 + (lane >> 4)) ^ (lane & 7)) * 8;

  for (int k0 = 0; k0 < KD; k0 += 64) {
    size_t kb = (size_t)k0 * 2;
#pragma unroll
    for (int t = 0; t < 4; ++t) {
      load_lds16(aP[t] + kb, &As[(wid * 32 + t * 8) * 64]);
      load_lds16(bP[t] + kb, &Bs[(wid * 32 + t * 8) * 64]);
    }
    __syncthreads();
#pragma unroll
    for (int kk = 0; kk < 2; ++kk) {
      bf16x8 af[4], bfr[4];
#pragma unroll
      for (int m2 = 0; m2 < 4; ++m2) af[m2] = *(const bf16x8*)&As[rA[m2] + cS[kk]];
#pragma unroll
      for (int n2 = 0; n2 < 4; ++n2) bfr[n2] = *(const bf16x8*)&Bs[rB[n2] + cS[kk]];
#pragma unroll
      for (int m2 = 0; m2 < 4; ++m2)
#pragma unroll
        for (int n2 = 0; n2 < 4; ++n2)
          acc[m2][n2] = __builtin_amdgcn_mfma_f32_16x16x32_bf16(af[m2], bfr[n2], acc[m2][n2], 0, 0, 0);
    }
    __syncthreads();
  }

  // epilogue; C/D frag: col = lane&15, row = (lane>>4)*4 + reg  [verified m89/m91]
#pragma unroll
  for (int m2 = 0; m2 < 4; ++m2) {
    int rb = wr * 64 + m2 * 16 + ((lane >> 4) << 2);
#pragma unroll
    for (int n2 = 0; n2 < 4; ++n2) {
      int col = ct * 128 + wc * 64 + n2 * 16 + (lane & 15);
#pragma unroll
      for (int r = 0; r < 4; ++r) {
        int grow = i0 + rb + r;
        if (grow < cnt) {
          float v = acc[m2][n2][r];
          if constexpr (EPI == 1) {
            v = fmaxf(v, 0.f);
            Hout[(size_t)(rowbase + grow) * NDT + col] = (__bf16)(v * v);
          } else {
            atomicAdd(&Yout[(size_t)toksL[rb + r] * NDT + col], v * sclL[rb + r]);
          }
        }
      }
    }
  }
}

// ---------------- GEMM2a (shared -> y plain store), 64x128 tile, 4 waves, 4 blocks/CU ----------------
__global__ __launch_bounds__(256, 4) void gemm2s_kernel(
    const __bf16* __restrict__ A, const __bf16* __restrict__ B,
    float* __restrict__ Yout) {
  constexpr int KD = HDIM;         // 1408
  int nwg = gridDim.x;
  int lin = (blockIdx.x & 7) * (nwg >> 3) + (blockIdx.x >> 3);
  int rem = lin % 32;
  int rt = (lin / 32) * 4 + (rem & 3);   // 0..127
  int ct = rem >> 2;                     // 0..7
  int i0 = rt << 6;                      // 64 rows per tile

  __shared__ __align__(16) __bf16 As[64 * 64];    // 8 KB
  __shared__ __align__(16) __bf16 Bs[128 * 64];   // 16 KB

  int tid = threadIdx.x, lane = tid & 63, wid = tid >> 6;

  int rsub = lane >> 3, csub = lane & 7;
  int csw = (csub ^ rsub) * 16;
  const char* gA[2];
  const char* gB[4];
  const char* Bg = (const char*)B + (size_t)8 * DDIM * KD * 2;   // shared B2 slice
#pragma unroll
  for (int q = 0; q < 2; ++q) {
    int row = (wid * 2 + q) * 8 + rsub;                 // 0..63
    gA[q] = (const char*)A + (size_t)(i0 + row) * (KD * 2) + csw;
  }
#pragma unroll
  for (int q = 0; q < 4; ++q) {
    int row = (wid * 4 + q) * 8 + rsub;                 // 0..127
    gB[q] = Bg + (size_t)(ct * 128 + row) * (KD * 2) + csw;
  }

  f32x4 acc[4][2];
#pragma unroll
  for (int m2 = 0; m2 < 4; ++m2)
#pragma unroll
    for (int n2 = 0; n2 < 2; ++n2) acc[m2][n2] = f32x4{0.f, 0.f, 0.f, 0.f};

  int rA[4], rB[2], cS[2];
#pragma unroll
  for (int m2 = 0; m2 < 4; ++m2) rA[m2] = (m2 * 16 + (lane & 15)) * 64;
#pragma unroll
  for (int n2 = 0; n2 < 2; ++n2) rB[n2] = (wid * 32 + n2 * 16 + (lane & 15)) * 64;
#pragma unroll
  for (int kk = 0; kk < 2; ++kk) cS[kk] = ((kk * 4 + (lane >> 4)) ^ (lane & 7)) * 8;

  for (int k0 = 0; k0 < KD; k0 += 64) {
    size_t kb = (size_t)k0 * 2;
#pragma unroll
    for (int q = 0; q < 2; ++q)
      load_lds16(gA[q] + kb, &As[((wid * 2 + q) * 8) * 64]);
#pragma unroll
    for (int q = 0; q < 4; ++q)
      load_lds16(gB[q] + kb, &Bs[((wid * 4 + q) * 8) * 64]);
    __syncthreads();
#pragma unroll
    for (int kk = 0; kk < 2; ++kk) {
      bf16x8 af[4], bfr[2];
#pragma unroll
      for (int m2 = 0; m2 < 4; ++m2) af[m2] = *(const bf16x8*)&As[rA[m2] + cS[kk]];
#pragma unroll
      for (int n2 = 0; n2 < 2; ++n2) bfr[n2] = *(const bf16x8*)&Bs[rB[n2] + cS[kk]];
#pragma unroll
      for (int m2 = 0; m2 < 4; ++m2)
#pragma unroll
        for (int n2 = 0; n2 < 2; ++n2)
          acc[m2][n2] = __builtin_amdgcn_mfma_f32_16x16x32_bf16(af[m2], bfr[n2], acc[m2][n2], 0, 0, 0);
    }
    __syncthreads();
  }

#pragma unroll
  for (int m2 = 0; m2 < 4; ++m2) {
    int rb = m2 * 16 + ((lane >> 4) << 2);
#pragma unroll
    for (int n2 = 0; n2 < 2; ++n2) {
      int col = ct * 128 + wid * 32 + n2 * 16 + (lane & 15);
#pragma unroll
      for (int r = 0; r < 4; ++r)
        Yout[(size_t)(i0 + rb + r) * DDIM + col] = acc[m2][n2][r];
    }
  }
}

extern "C" void kernel_launch(void* const* d_in, const int* in_sizes, int n_in,
                              void* d_out, int out_size, void* d_ws, size_t ws_size,
                              hipStream_t stream) {
  const float* x      = (const float*)d_in[0];
  const float* rw     = (const float*)d_in[1];
  const float* wfc    = (const float*)d_in[2];
  const float* wproj  = (const float*)d_in[3];
  const float* wsfc   = (const float*)d_in[4];
  const float* wsproj = (const float*)d_in[5];
  float* y = (float*)d_out;

  char* ws = (char*)d_ws;
  size_t off = 0;
  auto alloc = [&](size_t bytes) {
    void* p = ws + off;
    off += (bytes + 1023) & ~(size_t)1023;
    return p;
  };
  __bf16* xbf      = (__bf16*)alloc((size_t)NTOK * DDIM * 2);          // 16 MB
  __bf16* B1       = (__bf16*)alloc((size_t)9 * HDIM * DDIM * 2);      // 26 MB [9][1408][1024]
  __bf16* B2       = (__bf16*)alloc((size_t)9 * DDIM * HDIM * 2);      // 26 MB [9][1024][1408]
  __bf16* H        = (__bf16*)alloc((size_t)NROWS * HDIM * 2);         // 81 MB
  int*    tok_row  = (int*)alloc((size_t)NROWS * 4);
  float*  scale_row= (float*)alloc((size_t)NROWS * 4);
  int2*   e01      = (int2*)alloc((size_t)NTOK * 8);
  float2* p01      = (float2*)alloc((size_t)NTOK * 8);
  int*    counts   = (int*)alloc(1024);
  float*  psum_part= (float*)alloc(256 * 8 * 4);
  int*    fcnt_part= (int*)alloc(256 * 8 * 4);
  (void)ws_size; (void)out_size; (void)in_sizes; (void)n_in;

  tconv3_kernel<<<dim3(44, 22, 18), 256, 0, stream>>>(wfc, B1, wsfc, wproj, B2, wsproj);
  router_kernel<<<256, 256, 0, stream>>>(x, rw, xbf, e01, p01, tok_row, scale_row,
                                         psum_part, fcnt_part);
  dispatch_kernel<<<1, 256, 0, stream>>>(e01, p01, tok_row, scale_row, counts,
                                         psum_part, fcnt_part, y + YN);
  // GEMM1: H = relu(gather(x) @ B1)^2 ; 128x128 tiles: (64 + 8*20) rt * 11 ct = 2464
  gemm_kernel<1024, 1408, true, 1, 0><<<2464, 256, 0, stream>>>(
      xbf, B1, H, nullptr, counts, tok_row, scale_row);
  // GEMM2a (shared): y = H_shared @ B2s (plain store; 64x128 tiles, 1024 blocks = 4/CU)
  gemm2s_kernel<<<1024, 256, 0, stream>>>(H, B2, y);
  // GEMM2b (experts): y += scale * (H_exp @ B2)  (atomicAdd on top)
  gemm_kernel<1408, 1024, false, 2, 2><<<1280, 256, 0, stream>>>(
      H, B2, nullptr, y, counts, tok_row, scale_row);
}

// Round 20
// 302.650 us; speedup vs baseline: 1.0224x; 1.0224x over previous
//
#include <hip/hip_runtime.h>

// MoE forward, MI355X. fp32 router/dispatch (exact top-k), bf16 MFMA grouped
// GEMMs (9 groups = 8 experts + shared), zero-elim shared-store split.
// R20: persistent-CTA grids kill scheduling-round tails. GEMM2b was 1280
// blocks / 1024 slots = 1.25 rounds; the 256-block straggler round runs at
// 1 block/CU (R2/R8: ~2x slower/step) ~= 25-30us. Now: 1024 blocks grid-
// stride over virtual tiles (XCD remap on vt; 1024%8=0 keeps XCD chunking).
// GEMM1 same (2464 tiles over 1024 blocks). Per-tile body byte-identical to
// the 13x-verified R8 structure. Ledger: no >4 waves/EU (R9 spill), no dbuf
// (R14), no mega-fusion (R11/R12), no fine-phase (R6/R7).

#define NTOK 8192
#define DDIM 1024
#define HDIM 1408
#define CAP  2560
#define NROWS (NTOK + 8*CAP)   // 28672 GEMM rows: [0,8192) shared, then 8*2560 expert slots
#define YN   8388608           // NTOK*DDIM

typedef __bf16 bf16x8 __attribute__((ext_vector_type(8)));
typedef float  f32x4  __attribute__((ext_vector_type(4)));

typedef __attribute__((address_space(1))) void gvoid_t;
typedef __attribute__((address_space(3))) void svoid_t;

static __device__ __forceinline__ void load_lds16(const void* g, void* l) {
  // 16B per lane, LDS dest = wave-uniform base + lane*16 (linear)
  __builtin_amdgcn_global_load_lds((gvoid_t*)g, (svoid_t*)l, 16, 0, 0);
}

// ------- transpose+convert v3: one launch for all 4 weight tensors -------
__global__ __launch_bounds__(256) void tconv3_kernel(
    const float* __restrict__ wfc, __bf16* __restrict__ B1,
    const float* __restrict__ wsfc,
    const float* __restrict__ wproj, __bf16* __restrict__ B2,
    const float* __restrict__ wsproj) {
  __shared__ float t[64][33];
  int z = blockIdx.z, tid = threadIdx.x;
  const float* ip;
  __bf16* op;
  int R, C;
  if (z < 9) {
    if (blockIdx.y >= 16) return;          // B1 geometry: 44 x 16
    R = 1024; C = 1408;
    ip = (z < 8) ? wfc + (size_t)z * R * C : wsfc;
    op = (z < 8) ? B1 + (size_t)z * (size_t)C * R : B1 + (size_t)8 * (size_t)C * R;
  } else {
    if (blockIdx.x >= 32) return;          // B2 geometry: 32 x 22
    R = 1408; C = 1024;
    int e = z - 9;
    ip = (e < 8) ? wproj + (size_t)e * R * C : wsproj;
    op = (e < 8) ? B2 + (size_t)e * (size_t)C * R : B2 + (size_t)8 * (size_t)C * R;
  }
  int c0 = blockIdx.x * 32, r0 = blockIdx.y * 64;
  int tx = tid & 31, ty = tid >> 5;          // read: 8 rows/pass, 128B/row coalesced
#pragma unroll
  for (int k = 0; k < 8; ++k)
    t[ty + k * 8][tx] = ip[(size_t)(r0 + ty + k * 8) * C + c0 + tx];
  __syncthreads();
  int cl = tid >> 3, rq = (tid & 7) * 8;     // write: one bf16x8 (16B) per thread
  bf16x8 o;                                  // LDS bank = (8q+j+p)%32 -> 2-way (free)
#pragma unroll
  for (int j = 0; j < 8; ++j) o[j] = (__bf16)t[rq + j][cl];
  *(bf16x8*)(op + (size_t)(c0 + cl) * R + r0 + rq) = o;
}

// ------- router (+ fused x->bf16 convert): fp32 logits, softmax, top-2, renorm -------
__global__ __launch_bounds__(256) void router_kernel(
    const float* __restrict__ x, const float* __restrict__ rw,
    __bf16* __restrict__ xbf,
    int2* __restrict__ e01, float2* __restrict__ p01,
    int* __restrict__ tok_row, float* __restrict__ scale_row,
    float* __restrict__ psum_part, int* __restrict__ fcnt_part) {
  __shared__ float rwl[8 * 1024];
  __shared__ float ps[8];
  __shared__ int fc[8];
  int tid = threadIdx.x;
  if (tid < 8) { ps[tid] = 0.f; fc[tid] = 0; }
  float4* rl4 = (float4*)rwl;
  const float4* rg4 = (const float4*)rw;
#pragma unroll
  for (int j = 0; j < 8; ++j) rl4[tid + 256 * j] = rg4[tid + 256 * j];
  __syncthreads();
  int lane = tid & 63, wid = tid >> 6;
  for (int it = 0; it < 8; ++it) {
    int t = blockIdx.x * 32 + wid * 8 + it;
    const float4* xt = (const float4*)(x + (size_t)t * DDIM);
    float a[8];
#pragma unroll
    for (int e = 0; e < 8; ++e) a[e] = 0.f;
    float4 v[4];
#pragma unroll
    for (int jj = 0; jj < 4; ++jj) {
      v[jj] = xt[lane * 4 + jj];
#pragma unroll
      for (int e = 0; e < 8; ++e) {
        float4 w = rl4[e * 256 + lane * 4 + jj];
        a[e] += v[jj].x * w.x + v[jj].y * w.y + v[jj].z * w.z + v[jj].w * w.w;
      }
    }
    {
      bf16x8 o0, o1;
#pragma unroll
      for (int jj = 0; jj < 2; ++jj) {
        o0[jj * 4 + 0] = (__bf16)v[jj].x; o0[jj * 4 + 1] = (__bf16)v[jj].y;
        o0[jj * 4 + 2] = (__bf16)v[jj].z; o0[jj * 4 + 3] = (__bf16)v[jj].w;
        o1[jj * 4 + 0] = (__bf16)v[jj + 2].x; o1[jj * 4 + 1] = (__bf16)v[jj + 2].y;
        o1[jj * 4 + 2] = (__bf16)v[jj + 2].z; o1[jj * 4 + 3] = (__bf16)v[jj + 2].w;
      }
      __bf16* xo = xbf + (size_t)t * DDIM + lane * 16;
      *(bf16x8*)xo = o0;
      *(bf16x8*)(xo + 8) = o1;
    }
#pragma unroll
    for (int off = 32; off >= 1; off >>= 1)
#pragma unroll
      for (int e = 0; e < 8; ++e) a[e] += __shfl_xor(a[e], off);
    if (lane == 0) {
      int am = 0; float m = a[0];
      for (int e = 1; e < 8; ++e) if (a[e] > m) { m = a[e]; am = e; }
      float s = 0.f, ex[8];
      for (int e = 0; e < 8; ++e) { ex[e] = expf(a[e] - m); s += ex[e]; }
      float inv = 1.f / s;
      int am2 = -1; float m2 = -3.4e38f;
      for (int e = 0; e < 8; ++e) if (e != am && a[e] > m2) { m2 = a[e]; am2 = e; }
      float p0 = ex[am] * inv, p1 = ex[am2] * inv;
      float rn = 1.f / (p0 + p1 + 1e-9f);
      e01[t] = make_int2(am, am2);
      p01[t] = make_float2(p0 * rn, p1 * rn);
      tok_row[t] = t;            // shared-group rows: identity gather, weight 1
      scale_row[t] = 1.f;
      atomicAdd(&fc[am], 1);
      for (int e = 0; e < 8; ++e) atomicAdd(&ps[e], ex[e] * inv);
    }
  }
  __syncthreads();
  if (tid < 8) { psum_part[blockIdx.x * 8 + tid] = ps[tid]; fcnt_part[blockIdx.x * 8 + tid] = fc[tid]; }
}

// ------- dispatch (+stat reduce +aux): stable rank within expert, capacity drop -------
__global__ __launch_bounds__(256) void dispatch_kernel(
    const int2* __restrict__ e01, const float2* __restrict__ p01,
    int* __restrict__ tok_row, float* __restrict__ scale_row, int* __restrict__ counts,
    const float* __restrict__ psum_part, const int* __restrict__ fcnt_part,
    float* __restrict__ aux_out) {
  __shared__ int lcnt[256][8];
  __shared__ float wps[4][8];
  __shared__ int wfcs[4][8];
  __shared__ float aps[8];
  __shared__ int afc[8];
  int tid = threadIdx.x, lane = tid & 63, w = tid >> 6;
  float s[8]; int c[8];
#pragma unroll
  for (int e = 0; e < 8; ++e) { s[e] = psum_part[tid * 8 + e]; c[e] = fcnt_part[tid * 8 + e]; }
#pragma unroll
  for (int off = 32; off >= 1; off >>= 1)
#pragma unroll
    for (int e = 0; e < 8; ++e) { s[e] += __shfl_xor(s[e], off); c[e] += __shfl_xor(c[e], off); }
  if (lane == 0) {
#pragma unroll
    for (int e = 0; e < 8; ++e) { wps[w][e] = s[e]; wfcs[w][e] = c[e]; }
  }
  int my[8];
#pragma unroll
  for (int e = 0; e < 8; ++e) my[e] = 0;
  int base = tid * 64;  // 256 threads * 64 entries = 16384 = N*K, contiguous => stable
  for (int j = 0; j < 64; ++j) {
    int ent = base + j; int t = ent >> 1;
    int2 ee = e01[t];
    int ex = (ent & 1) ? ee.y : ee.x;
    my[ex]++;
  }
#pragma unroll
  for (int e = 0; e < 8; ++e) lcnt[tid][e] = my[e];
  __syncthreads();
  if (tid < 8) {
    aps[tid] = wps[0][tid] + wps[1][tid] + wps[2][tid] + wps[3][tid];
    afc[tid] = wfcs[0][tid] + wfcs[1][tid] + wfcs[2][tid] + wfcs[3][tid];
    int run = 0;
    for (int i = 0; i < 256; ++i) { int cc = lcnt[i][tid]; lcnt[i][tid] = run; run += cc; }
    counts[tid] = run < CAP ? run : CAP;
  }
  __syncthreads();
  int offs[8];
#pragma unroll
  for (int e = 0; e < 8; ++e) offs[e] = lcnt[tid][e];
  for (int j = 0; j < 64; ++j) {
    int ent = base + j; int t = ent >> 1; int k = ent & 1;
    int2 ee = e01[t];
    int ex = k ? ee.y : ee.x;
    float pr = k ? p01[t].y : p01[t].x;
    int pos = offs[ex]++;
    if (pos < CAP) {
      int row = NTOK + ex * CAP + pos;
      tok_row[row] = t;
      scale_row[row] = pr;
    }
  }
  if (tid == 0) {
    float t = 0.f;
    for (int e = 0; e < 8; ++e) t += ((float)afc[e] / 8192.f) * (aps[e] / 8192.f);
    *aux_out = 0.08f * t;  // AUX_COEF * E = 0.01 * 8
  }
}

// ---------------- grouped GEMM, persistent-CTA, 128x128 tile, BK=64, 4 waves ----------------
// Per-tile body = R8 structure (13x verified). Grid = 1024 blocks (exactly
// 4/CU); each strides virtual tiles vt = bid, bid+1024, ... < NT. XCD remap
// applied to vt (1024%8==0 keeps same-XCD chunks). Inactive tiles skipped
// uniformly. Loop-top barrier protects toksL WAR across tiles.
// RANGE: 0 = shared+expert tiles (GEMM1), 2 = expert-only (GEMM2b).
// EPI: 1 = H-store bf16(relu^2); 2 = atomicAdd(y, v*scale).
template <int KD, int NDT, bool GATHER, int EPI, int RANGE, int NT>
__global__ __launch_bounds__(256, 4) void gemm_kernel(
    const __bf16* __restrict__ A, const __bf16* __restrict__ B,
    __bf16* __restrict__ Hout, float* __restrict__ Yout,
    const int* __restrict__ counts, const int* __restrict__ tok_row,
    const float* __restrict__ scale_row) {
  constexpr int NCT = NDT / 128;
  constexpr int SH = NTOK / 128;   // 64 shared row-tiles
  constexpr int ET = CAP / 128;    // 20 expert row-tiles (worst case)

  __shared__ __align__(16) __bf16 As[128 * 64];   // 16 KB
  __shared__ __align__(16) __bf16 Bs[128 * 64];   // 16 KB
  __shared__ int   toksL[128];
  __shared__ float sclL[128];

  int tid = threadIdx.x, lane = tid & 63, wid = tid >> 6;

  // tile-independent lane constants (hoisted)
  int rsub = lane >> 3, csub = lane & 7;
  int csw = (csub ^ rsub) * 16;
  int wr = wid >> 1, wc = wid & 1;
  int rA[4], rB[4], cS[2];
#pragma unroll
  for (int m2 = 0; m2 < 4; ++m2) rA[m2] = (wr * 64 + m2 * 16 + (lane & 15)) * 64;
#pragma unroll
  for (int n2 = 0; n2 < 4; ++n2) rB[n2] = (wc * 64 + n2 * 16 + (lane & 15)) * 64;
#pragma unroll
  for (int kk = 0; kk < 2; ++kk) cS[kk] = ((kk * 4 + (lane >> 4)) ^ (lane & 7)) * 8;

  for (int vt = blockIdx.x; vt < NT; vt += gridDim.x) {
    // XCD bijective remap + 4-rt chunks on the virtual tile id
    int lin = (vt & 7) * (NT >> 3) + (vt >> 3);
    int rem = lin % (4 * NCT);
    int rt = (lin / (4 * NCT)) * 4 + (rem & 3);
    int ct = rem >> 2;

    int g, i0, rowbase;
    if (RANGE == 2) { g = rt / ET; i0 = (rt % ET) << 7; rowbase = NTOK + g * CAP; }
    else {
      if (rt < SH) { g = 8; rowbase = 0; i0 = rt << 7; }
      else { int r = rt - SH; g = r / ET; i0 = (r % ET) << 7; rowbase = NTOK + g * CAP; }
    }
    int cnt = (g == 8) ? NTOK : counts[g];
    if (i0 >= cnt) continue;  // uniform skip (cheap inactive tile)

    __syncthreads();          // protect toksL/sclL WAR vs previous tile's epilogue
    if (tid < 128) {
      int i = i0 + tid; if (i > cnt - 1) i = cnt - 1;  // pad rows duplicate last valid
      toksL[tid] = tok_row[rowbase + i];
      if (EPI == 2) sclL[tid] = scale_row[rowbase + i];
    }
    __syncthreads();

    const char* aP[4];
    const char* bP[4];
    const char* Bg = (const char*)B + (size_t)g * NDT * KD * 2;
#pragma unroll
    for (int t = 0; t < 4; ++t) {
      int ia = wid * 32 + t * 8 + rsub;
      size_t arow = GATHER ? (size_t)toksL[ia] : (size_t)(rowbase + i0 + ia);
      aP[t] = (const char*)A + arow * (size_t)(KD * 2) + csw;
      int ib = ct * 128 + wid * 32 + t * 8 + rsub;
      bP[t] = Bg + (size_t)ib * (KD * 2) + csw;
    }

    f32x4 acc[4][4];
#pragma unroll
    for (int m2 = 0; m2 < 4; ++m2)
#pragma unroll
      for (int n2 = 0; n2 < 4; ++n2) acc[m2][n2] = f32x4{0.f, 0.f, 0.f, 0.f};

    // m97 structure: stage -> sync -> compute -> sync, single buffer.
    for (int k0 = 0; k0 < KD; k0 += 64) {
      size_t kb = (size_t)k0 * 2;
#pragma unroll
      for (int t = 0; t < 4; ++t) {
        load_lds16(aP[t] + kb, &As[(wid * 32 + t * 8) * 64]);
        load_lds16(bP[t] + kb, &Bs[(wid * 32 + t * 8) * 64]);
      }
      __syncthreads();   // compiler inserts s_waitcnt vmcnt(0) before barrier
#pragma unroll
      for (int kk = 0; kk < 2; ++kk) {
        bf16x8 af[4], bfr[4];
#pragma unroll
        for (int m2 = 0; m2 < 4; ++m2) af[m2] = *(const bf16x8*)&As[rA[m2] + cS[kk]];
#pragma unroll
        for (int n2 = 0; n2 < 4; ++n2) bfr[n2] = *(const bf16x8*)&Bs[rB[n2] + cS[kk]];
#pragma unroll
        for (int m2 = 0; m2 < 4; ++m2)
#pragma unroll
          for (int n2 = 0; n2 < 4; ++n2)
            acc[m2][n2] = __builtin_amdgcn_mfma_f32_16x16x32_bf16(af[m2], bfr[n2], acc[m2][n2], 0, 0, 0);
      }
      __syncthreads();   // protect LDS reuse next iteration
    }

    // epilogue; C/D frag: col = lane&15, row = (lane>>4)*4 + reg  [verified m89/m91]
#pragma unroll
    for (int m2 = 0; m2 < 4; ++m2) {
      int rb = wr * 64 + m2 * 16 + ((lane >> 4) << 2);
#pragma unroll
      for (int n2 = 0; n2 < 4; ++n2) {
        int col = ct * 128 + wc * 64 + n2 * 16 + (lane & 15);
#pragma unroll
        for (int r = 0; r < 4; ++r) {
          int grow = i0 + rb + r;
          if (grow < cnt) {
            float v = acc[m2][n2][r];
            if constexpr (EPI == 1) {
              v = fmaxf(v, 0.f);
              Hout[(size_t)(rowbase + grow) * NDT + col] = (__bf16)(v * v);
            } else {
              atomicAdd(&Yout[(size_t)toksL[rb + r] * NDT + col], v * sclL[rb + r]);
            }
          }
        }
      }
    }
  }
}

// ---------------- GEMM2a (shared -> y plain store), 64x128 tile, 4 waves, exactly 1 round ----------------
__global__ __launch_bounds__(256, 4) void gemm2s_kernel(
    const __bf16* __restrict__ A, const __bf16* __restrict__ B,
    float* __restrict__ Yout) {
  constexpr int KD = HDIM;         // 1408
  int nwg = gridDim.x;
  int lin = (blockIdx.x & 7) * (nwg >> 3) + (blockIdx.x >> 3);
  int rem = lin % 32;
  int rt = (lin / 32) * 4 + (rem & 3);   // 0..127
  int ct = rem >> 2;                     // 0..7
  int i0 = rt << 6;                      // 64 rows per tile

  __shared__ __align__(16) __bf16 As[64 * 64];    // 8 KB
  __shared__ __align__(16) __bf16 Bs[128 * 64];   // 16 KB

  int tid = threadIdx.x, lane = tid & 63, wid = tid >> 6;

  int rsub = lane >> 3, csub = lane & 7;
  int csw = (csub ^ rsub) * 16;
  const char* gA[2];
  const char* gB[4];
  const char* Bg = (const char*)B + (size_t)8 * DDIM * KD * 2;   // shared B2 slice
#pragma unroll
  for (int q = 0; q < 2; ++q) {
    int row = (wid * 2 + q) * 8 + rsub;                 // 0..63
    gA[q] = (const char*)A + (size_t)(i0 + row) * (KD * 2) + csw;
  }
#pragma unroll
  for (int q = 0; q < 4; ++q) {
    int row = (wid * 4 + q) * 8 + rsub;                 // 0..127
    gB[q] = Bg + (size_t)(ct * 128 + row) * (KD * 2) + csw;
  }

  f32x4 acc[4][2];
#pragma unroll
  for (int m2 = 0; m2 < 4; ++m2)
#pragma unroll
    for (int n2 = 0; n2 < 2; ++n2) acc[m2][n2] = f32x4{0.f, 0.f, 0.f, 0.f};

  int rA[4], rB[2], cS[2];
#pragma unroll
  for (int m2 = 0; m2 < 4; ++m2) rA[m2] = (m2 * 16 + (lane & 15)) * 64;
#pragma unroll
  for (int n2 = 0; n2 < 2; ++n2) rB[n2] = (wid * 32 + n2 * 16 + (lane & 15)) * 64;
#pragma unroll
  for (int kk = 0; kk < 2; ++kk) cS[kk] = ((kk * 4 + (lane >> 4)) ^ (lane & 7)) * 8;

  for (int k0 = 0; k0 < KD; k0 += 64) {
    size_t kb = (size_t)k0 * 2;
#pragma unroll
    for (int q = 0; q < 2; ++q)
      load_lds16(gA[q] + kb, &As[((wid * 2 + q) * 8) * 64]);
#pragma unroll
    for (int q = 0; q < 4; ++q)
      load_lds16(gB[q] + kb, &Bs[((wid * 4 + q) * 8) * 64]);
    __syncthreads();
#pragma unroll
    for (int kk = 0; kk < 2; ++kk) {
      bf16x8 af[4], bfr[2];
#pragma unroll
      for (int m2 = 0; m2 < 4; ++m2) af[m2] = *(const bf16x8*)&As[rA[m2] + cS[kk]];
#pragma unroll
      for (int n2 = 0; n2 < 2; ++n2) bfr[n2] = *(const bf16x8*)&Bs[rB[n2] + cS[kk]];
#pragma unroll
      for (int m2 = 0; m2 < 4; ++m2)
#pragma unroll
        for (int n2 = 0; n2 < 2; ++n2)
          acc[m2][n2] = __builtin_amdgcn_mfma_f32_16x16x32_bf16(af[m2], bfr[n2], acc[m2][n2], 0, 0, 0);
    }
    __syncthreads();
  }

#pragma unroll
  for (int m2 = 0; m2 < 4; ++m2) {
    int rb = m2 * 16 + ((lane >> 4) << 2);
#pragma unroll
    for (int n2 = 0; n2 < 2; ++n2) {
      int col = ct * 128 + wid * 32 + n2 * 16 + (lane & 15);
#pragma unroll
      for (int r = 0; r < 4; ++r)
        Yout[(size_t)(i0 + rb + r) * DDIM + col] = acc[m2][n2][r];
    }
  }
}

extern "C" void kernel_launch(void* const* d_in, const int* in_sizes, int n_in,
                              void* d_out, int out_size, void* d_ws, size_t ws_size,
                              hipStream_t stream) {
  const float* x      = (const float*)d_in[0];
  const float* rw     = (const float*)d_in[1];
  const float* wfc    = (const float*)d_in[2];
  const float* wproj  = (const float*)d_in[3];
  const float* wsfc   = (const float*)d_in[4];
  const float* wsproj = (const float*)d_in[5];
  float* y = (float*)d_out;

  char* ws = (char*)d_ws;
  size_t off = 0;
  auto alloc = [&](size_t bytes) {
    void* p = ws + off;
    off += (bytes + 1023) & ~(size_t)1023;
    return p;
  };
  __bf16* xbf      = (__bf16*)alloc((size_t)NTOK * DDIM * 2);          // 16 MB
  __bf16* B1       = (__bf16*)alloc((size_t)9 * HDIM * DDIM * 2);      // 26 MB [9][1408][1024]
  __bf16* B2       = (__bf16*)alloc((size_t)9 * DDIM * HDIM * 2);      // 26 MB [9][1024][1408]
  __bf16* H        = (__bf16*)alloc((size_t)NROWS * HDIM * 2);         // 81 MB
  int*    tok_row  = (int*)alloc((size_t)NROWS * 4);
  float*  scale_row= (float*)alloc((size_t)NROWS * 4);
  int2*   e01      = (int2*)alloc((size_t)NTOK * 8);
  float2* p01      = (float2*)alloc((size_t)NTOK * 8);
  int*    counts   = (int*)alloc(1024);
  float*  psum_part= (float*)alloc(256 * 8 * 4);
  int*    fcnt_part= (int*)alloc(256 * 8 * 4);
  (void)ws_size; (void)out_size; (void)in_sizes; (void)n_in;

  tconv3_kernel<<<dim3(44, 22, 18), 256, 0, stream>>>(wfc, B1, wsfc, wproj, B2, wsproj);
  router_kernel<<<256, 256, 0, stream>>>(x, rw, xbf, e01, p01, tok_row, scale_row,
                                         psum_part, fcnt_part);
  dispatch_kernel<<<1, 256, 0, stream>>>(e01, p01, tok_row, scale_row, counts,
                                         psum_part, fcnt_part, y + YN);
  // GEMM1: H = relu(gather(x) @ B1)^2 ; 2464 virtual tiles over 1024 persistent blocks
  gemm_kernel<1024, 1408, true, 1, 0, 2464><<<1024, 256, 0, stream>>>(
      xbf, B1, H, nullptr, counts, tok_row, scale_row);
  // GEMM2a (shared): y = H_shared @ B2s (plain store; 1024 blocks = exactly 1 round)
  gemm2s_kernel<<<1024, 256, 0, stream>>>(H, B2, y);
  // GEMM2b (experts): y += scale*(H_exp @ B2); 1280 virtual tiles over 1024 blocks
  gemm_kernel<1408, 1024, false, 2, 2, 1280><<<1024, 256, 0, stream>>>(
      H, B2, nullptr, y, counts, tok_row, scale_row);
}

// Round 22
// 299.148 us; speedup vs baseline: 1.0344x; 1.0117x over previous
//
#include <hip/hip_runtime.h>

// MoE forward, MI355X. fp32 router/dispatch (exact top-k), bf16 MFMA grouped
// GEMMs, zero-elim shared-store split, persistent-CTA grids.
// R22: fix R21's one-line addressing bug. GEMM2b was launched with
// A = H + NTOK*HDIM while the kernel's rowbase = NTOK + g*CAP already
// indexes the expert region -> double offset, read past H into Eout/poison
// (absmax 7.14). Now A = H (R20-verified addressing). Design unchanged:
// GEMM2b plain-stores bf16 Eout[slot][col] (no 67MB atomic RMW stream);
// combine kernel does y[t] += p0*E[s0] + p1*E[s1] via dispatch-written
// inverse map islot[t*2+k] (-1 = dropped, matches reference keep=0).
// Ledger: no >4 waves/EU (R9), no dbuf (R14), no fine-phase (R6/R7),
// no mega-fusion (R11/R12), persistent grids (R20).

#define NTOK 8192
#define DDIM 1024
#define HDIM 1408
#define CAP  2560
#define NROWS (NTOK + 8*CAP)   // 28672 GEMM rows: [0,8192) shared, then 8*2560 expert slots
#define YN   8388608           // NTOK*DDIM

typedef __bf16 bf16x8 __attribute__((ext_vector_type(8)));
typedef __bf16 bf16x4 __attribute__((ext_vector_type(4)));
typedef float  f32x4  __attribute__((ext_vector_type(4)));

typedef __attribute__((address_space(1))) void gvoid_t;
typedef __attribute__((address_space(3))) void svoid_t;

static __device__ __forceinline__ void load_lds16(const void* g, void* l) {
  // 16B per lane, LDS dest = wave-uniform base + lane*16 (linear)
  __builtin_amdgcn_global_load_lds((gvoid_t*)g, (svoid_t*)l, 16, 0, 0);
}

// ------- transpose+convert v3: one launch for all 4 weight tensors -------
__global__ __launch_bounds__(256) void tconv3_kernel(
    const float* __restrict__ wfc, __bf16* __restrict__ B1,
    const float* __restrict__ wsfc,
    const float* __restrict__ wproj, __bf16* __restrict__ B2,
    const float* __restrict__ wsproj) {
  __shared__ float t[64][33];
  int z = blockIdx.z, tid = threadIdx.x;
  const float* ip;
  __bf16* op;
  int R, C;
  if (z < 9) {
    if (blockIdx.y >= 16) return;          // B1 geometry: 44 x 16
    R = 1024; C = 1408;
    ip = (z < 8) ? wfc + (size_t)z * R * C : wsfc;
    op = (z < 8) ? B1 + (size_t)z * (size_t)C * R : B1 + (size_t)8 * (size_t)C * R;
  } else {
    if (blockIdx.x >= 32) return;          // B2 geometry: 32 x 22
    R = 1408; C = 1024;
    int e = z - 9;
    ip = (e < 8) ? wproj + (size_t)e * R * C : wsproj;
    op = (e < 8) ? B2 + (size_t)e * (size_t)C * R : B2 + (size_t)8 * (size_t)C * R;
  }
  int c0 = blockIdx.x * 32, r0 = blockIdx.y * 64;
  int tx = tid & 31, ty = tid >> 5;          // read: 8 rows/pass, 128B/row coalesced
#pragma unroll
  for (int k = 0; k < 8; ++k)
    t[ty + k * 8][tx] = ip[(size_t)(r0 + ty + k * 8) * C + c0 + tx];
  __syncthreads();
  int cl = tid >> 3, rq = (tid & 7) * 8;     // write: one bf16x8 (16B) per thread
  bf16x8 o;                                  // LDS bank = (8q+j+p)%32 -> 2-way (free)
#pragma unroll
  for (int j = 0; j < 8; ++j) o[j] = (__bf16)t[rq + j][cl];
  *(bf16x8*)(op + (size_t)(c0 + cl) * R + r0 + rq) = o;
}

// ------- router (+ fused x->bf16 convert): fp32 logits, softmax, top-2, renorm -------
__global__ __launch_bounds__(256) void router_kernel(
    const float* __restrict__ x, const float* __restrict__ rw,
    __bf16* __restrict__ xbf,
    int2* __restrict__ e01, float2* __restrict__ p01,
    int* __restrict__ tok_row, float* __restrict__ scale_row,
    float* __restrict__ psum_part, int* __restrict__ fcnt_part) {
  __shared__ float rwl[8 * 1024];
  __shared__ float ps[8];
  __shared__ int fc[8];
  int tid = threadIdx.x;
  if (tid < 8) { ps[tid] = 0.f; fc[tid] = 0; }
  float4* rl4 = (float4*)rwl;
  const float4* rg4 = (const float4*)rw;
#pragma unroll
  for (int j = 0; j < 8; ++j) rl4[tid + 256 * j] = rg4[tid + 256 * j];
  __syncthreads();
  int lane = tid & 63, wid = tid >> 6;
  for (int it = 0; it < 8; ++it) {
    int t = blockIdx.x * 32 + wid * 8 + it;
    const float4* xt = (const float4*)(x + (size_t)t * DDIM);
    float a[8];
#pragma unroll
    for (int e = 0; e < 8; ++e) a[e] = 0.f;
    float4 v[4];
#pragma unroll
    for (int jj = 0; jj < 4; ++jj) {
      v[jj] = xt[lane * 4 + jj];
#pragma unroll
      for (int e = 0; e < 8; ++e) {
        float4 w = rl4[e * 256 + lane * 4 + jj];
        a[e] += v[jj].x * w.x + v[jj].y * w.y + v[jj].z * w.z + v[jj].w * w.w;
      }
    }
    {
      bf16x8 o0, o1;
#pragma unroll
      for (int jj = 0; jj < 2; ++jj) {
        o0[jj * 4 + 0] = (__bf16)v[jj].x; o0[jj * 4 + 1] = (__bf16)v[jj].y;
        o0[jj * 4 + 2] = (__bf16)v[jj].z; o0[jj * 4 + 3] = (__bf16)v[jj].w;
        o1[jj * 4 + 0] = (__bf16)v[jj + 2].x; o1[jj * 4 + 1] = (__bf16)v[jj + 2].y;
        o1[jj * 4 + 2] = (__bf16)v[jj + 2].z; o1[jj * 4 + 3] = (__bf16)v[jj + 2].w;
      }
      __bf16* xo = xbf + (size_t)t * DDIM + lane * 16;
      *(bf16x8*)xo = o0;
      *(bf16x8*)(xo + 8) = o1;
    }
#pragma unroll
    for (int off = 32; off >= 1; off >>= 1)
#pragma unroll
      for (int e = 0; e < 8; ++e) a[e] += __shfl_xor(a[e], off);
    if (lane == 0) {
      int am = 0; float m = a[0];
      for (int e = 1; e < 8; ++e) if (a[e] > m) { m = a[e]; am = e; }
      float s = 0.f, ex[8];
      for (int e = 0; e < 8; ++e) { ex[e] = expf(a[e] - m); s += ex[e]; }
      float inv = 1.f / s;
      int am2 = -1; float m2 = -3.4e38f;
      for (int e = 0; e < 8; ++e) if (e != am && a[e] > m2) { m2 = a[e]; am2 = e; }
      float p0 = ex[am] * inv, p1 = ex[am2] * inv;
      float rn = 1.f / (p0 + p1 + 1e-9f);
      e01[t] = make_int2(am, am2);
      p01[t] = make_float2(p0 * rn, p1 * rn);
      tok_row[t] = t;            // shared-group rows: identity gather, weight 1
      scale_row[t] = 1.f;
      atomicAdd(&fc[am], 1);
      for (int e = 0; e < 8; ++e) atomicAdd(&ps[e], ex[e] * inv);
    }
  }
  __syncthreads();
  if (tid < 8) { psum_part[blockIdx.x * 8 + tid] = ps[tid]; fcnt_part[blockIdx.x * 8 + tid] = fc[tid]; }
}

// ------- dispatch (+stat reduce +aux +inverse map): stable rank, capacity drop -------
__global__ __launch_bounds__(256) void dispatch_kernel(
    const int2* __restrict__ e01, const float2* __restrict__ p01,
    int* __restrict__ tok_row, float* __restrict__ scale_row, int* __restrict__ counts,
    int* __restrict__ islot,
    const float* __restrict__ psum_part, const int* __restrict__ fcnt_part,
    float* __restrict__ aux_out) {
  __shared__ int lcnt[256][8];
  __shared__ float wps[4][8];
  __shared__ int wfcs[4][8];
  __shared__ float aps[8];
  __shared__ int afc[8];
  int tid = threadIdx.x, lane = tid & 63, w = tid >> 6;
  float s[8]; int c[8];
#pragma unroll
  for (int e = 0; e < 8; ++e) { s[e] = psum_part[tid * 8 + e]; c[e] = fcnt_part[tid * 8 + e]; }
#pragma unroll
  for (int off = 32; off >= 1; off >>= 1)
#pragma unroll
    for (int e = 0; e < 8; ++e) { s[e] += __shfl_xor(s[e], off); c[e] += __shfl_xor(c[e], off); }
  if (lane == 0) {
#pragma unroll
    for (int e = 0; e < 8; ++e) { wps[w][e] = s[e]; wfcs[w][e] = c[e]; }
  }
  int my[8];
#pragma unroll
  for (int e = 0; e < 8; ++e) my[e] = 0;
  int base = tid * 64;  // 256 threads * 64 entries = 16384 = N*K, contiguous => stable
  for (int j = 0; j < 64; ++j) {
    int ent = base + j; int t = ent >> 1;
    int2 ee = e01[t];
    int ex = (ent & 1) ? ee.y : ee.x;
    my[ex]++;
  }
#pragma unroll
  for (int e = 0; e < 8; ++e) lcnt[tid][e] = my[e];
  __syncthreads();
  if (tid < 8) {
    aps[tid] = wps[0][tid] + wps[1][tid] + wps[2][tid] + wps[3][tid];
    afc[tid] = wfcs[0][tid] + wfcs[1][tid] + wfcs[2][tid] + wfcs[3][tid];
    int run = 0;
    for (int i = 0; i < 256; ++i) { int cc = lcnt[i][tid]; lcnt[i][tid] = run; run += cc; }
    counts[tid] = run < CAP ? run : CAP;
  }
  __syncthreads();
  int offs[8];
#pragma unroll
  for (int e = 0; e < 8; ++e) offs[e] = lcnt[tid][e];
  for (int j = 0; j < 64; ++j) {
    int ent = base + j; int t = ent >> 1; int k = ent & 1;
    int2 ee = e01[t];
    int ex = k ? ee.y : ee.x;
    float pr = k ? p01[t].y : p01[t].x;
    int pos = offs[ex]++;
    if (pos < CAP) {
      int row = NTOK + ex * CAP + pos;
      tok_row[row] = t;
      scale_row[row] = pr;
      islot[ent] = row;          // inverse map: entry (t,k) -> kept slot row
    } else {
      islot[ent] = -1;           // dropped (keep=0 in reference)
    }
  }
  if (tid == 0) {
    float t = 0.f;
    for (int e = 0; e < 8; ++e) t += ((float)afc[e] / 8192.f) * (aps[e] / 8192.f);
    *aux_out = 0.08f * t;  // AUX_COEF * E = 0.01 * 8
  }
}

// ---------------- grouped GEMM, persistent-CTA, 128x128 tile, BK=64, 4 waves ----------------
// Per-tile body = R8 structure (14x verified). RANGE: 0 = shared+expert
// (GEMM1), 2 = expert-only (GEMM2b). EPI: 1 = H-store bf16(relu^2);
// 4 = Eout plain bf16 store at slot = rowbase - NTOK + grow (A must be the
// UN-offset H base: rowbase already addresses the expert region -- R21 bug).
template <int KD, int NDT, bool GATHER, int EPI, int RANGE, int NT>
__global__ __launch_bounds__(256, 4) void gemm_kernel(
    const __bf16* __restrict__ A, const __bf16* __restrict__ B,
    __bf16* __restrict__ Hout,
    const int* __restrict__ counts, const int* __restrict__ tok_row) {
  constexpr int NCT = NDT / 128;
  constexpr int SH = NTOK / 128;   // 64 shared row-tiles
  constexpr int ET = CAP / 128;    // 20 expert row-tiles (worst case)

  __shared__ __align__(16) __bf16 As[128 * 64];   // 16 KB
  __shared__ __align__(16) __bf16 Bs[128 * 64];   // 16 KB
  __shared__ int toksL[128];

  int tid = threadIdx.x, lane = tid & 63, wid = tid >> 6;

  // tile-independent lane constants (hoisted)
  int rsub = lane >> 3, csub = lane & 7;
  int csw = (csub ^ rsub) * 16;
  int wr = wid >> 1, wc = wid & 1;
  int rA[4], rB[4], cS[2];
#pragma unroll
  for (int m2 = 0; m2 < 4; ++m2) rA[m2] = (wr * 64 + m2 * 16 + (lane & 15)) * 64;
#pragma unroll
  for (int n2 = 0; n2 < 4; ++n2) rB[n2] = (wc * 64 + n2 * 16 + (lane & 15)) * 64;
#pragma unroll
  for (int kk = 0; kk < 2; ++kk) cS[kk] = ((kk * 4 + (lane >> 4)) ^ (lane & 7)) * 8;

  for (int vt = blockIdx.x; vt < NT; vt += gridDim.x) {
    // XCD bijective remap + 4-rt chunks on the virtual tile id
    int lin = (vt & 7) * (NT >> 3) + (vt >> 3);
    int rem = lin % (4 * NCT);
    int rt = (lin / (4 * NCT)) * 4 + (rem & 3);
    int ct = rem >> 2;

    int g, i0, rowbase;
    if (RANGE == 2) { g = rt / ET; i0 = (rt % ET) << 7; rowbase = NTOK + g * CAP; }
    else {
      if (rt < SH) { g = 8; rowbase = 0; i0 = rt << 7; }
      else { int r = rt - SH; g = r / ET; i0 = (r % ET) << 7; rowbase = NTOK + g * CAP; }
    }
    int cnt = (g == 8) ? NTOK : counts[g];
    if (i0 >= cnt) continue;  // uniform skip (cheap inactive tile)

    if (GATHER) {
      __syncthreads();        // protect toksL WAR vs previous tile's staging
      if (tid < 128) {
        int i = i0 + tid; if (i > cnt - 1) i = cnt - 1;  // pad rows duplicate last valid
        toksL[tid] = tok_row[rowbase + i];
      }
      __syncthreads();
    }

    const char* aP[4];
    const char* bP[4];
    const char* Bg = (const char*)B + (size_t)g * NDT * KD * 2;
#pragma unroll
    for (int t = 0; t < 4; ++t) {
      int ia = wid * 32 + t * 8 + rsub;
      size_t arow = GATHER ? (size_t)toksL[ia] : (size_t)(rowbase + i0 + ia);
      aP[t] = (const char*)A + arow * (size_t)(KD * 2) + csw;
      int ib = ct * 128 + wid * 32 + t * 8 + rsub;
      bP[t] = Bg + (size_t)ib * (KD * 2) + csw;
    }

    f32x4 acc[4][4];
#pragma unroll
    for (int m2 = 0; m2 < 4; ++m2)
#pragma unroll
      for (int n2 = 0; n2 < 4; ++n2) acc[m2][n2] = f32x4{0.f, 0.f, 0.f, 0.f};

    // m97 structure: stage -> sync -> compute -> sync, single buffer.
    for (int k0 = 0; k0 < KD; k0 += 64) {
      size_t kb = (size_t)k0 * 2;
#pragma unroll
      for (int t = 0; t < 4; ++t) {
        load_lds16(aP[t] + kb, &As[(wid * 32 + t * 8) * 64]);
        load_lds16(bP[t] + kb, &Bs[(wid * 32 + t * 8) * 64]);
      }
      __syncthreads();   // compiler inserts s_waitcnt vmcnt(0) before barrier
#pragma unroll
      for (int kk = 0; kk < 2; ++kk) {
        bf16x8 af[4], bfr[4];
#pragma unroll
        for (int m2 = 0; m2 < 4; ++m2) af[m2] = *(const bf16x8*)&As[rA[m2] + cS[kk]];
#pragma unroll
        for (int n2 = 0; n2 < 4; ++n2) bfr[n2] = *(const bf16x8*)&Bs[rB[n2] + cS[kk]];
#pragma unroll
        for (int m2 = 0; m2 < 4; ++m2)
#pragma unroll
          for (int n2 = 0; n2 < 4; ++n2)
            acc[m2][n2] = __builtin_amdgcn_mfma_f32_16x16x32_bf16(af[m2], bfr[n2], acc[m2][n2], 0, 0, 0);
      }
      __syncthreads();   // protect LDS reuse next iteration
    }

    // epilogue; C/D frag: col = lane&15, row = (lane>>4)*4 + reg  [verified m89/m91]
#pragma unroll
    for (int m2 = 0; m2 < 4; ++m2) {
      int rb = wr * 64 + m2 * 16 + ((lane >> 4) << 2);
#pragma unroll
      for (int n2 = 0; n2 < 4; ++n2) {
        int col = ct * 128 + wc * 64 + n2 * 16 + (lane & 15);
#pragma unroll
        for (int r = 0; r < 4; ++r) {
          int grow = i0 + rb + r;
          if (grow < cnt) {
            float v = acc[m2][n2][r];
            if constexpr (EPI == 1) {
              v = fmaxf(v, 0.f);
              Hout[(size_t)(rowbase + grow) * NDT + col] = (__bf16)(v * v);
            } else {  // EPI == 4: slot-major bf16 store (combine applies prob)
              Hout[(size_t)(rowbase - NTOK + grow) * NDT + col] = (__bf16)v;
            }
          }
        }
      }
    }
  }
}

// ---------------- GEMM2a (shared -> y plain store), 64x128 tile, 4 waves, exactly 1 round ----------------
__global__ __launch_bounds__(256, 4) void gemm2s_kernel(
    const __bf16* __restrict__ A, const __bf16* __restrict__ B,
    float* __restrict__ Yout) {
  constexpr int KD = HDIM;         // 1408
  int nwg = gridDim.x;
  int lin = (blockIdx.x & 7) * (nwg >> 3) + (blockIdx.x >> 3);
  int rem = lin % 32;
  int rt = (lin / 32) * 4 + (rem & 3);   // 0..127
  int ct = rem >> 2;                     // 0..7
  int i0 = rt << 6;                      // 64 rows per tile

  __shared__ __align__(16) __bf16 As[64 * 64];    // 8 KB
  __shared__ __align__(16) __bf16 Bs[128 * 64];   // 16 KB

  int tid = threadIdx.x, lane = tid & 63, wid = tid >> 6;

  int rsub = lane >> 3, csub = lane & 7;
  int csw = (csub ^ rsub) * 16;
  const char* gA[2];
  const char* gB[4];
  const char* Bg = (const char*)B + (size_t)8 * DDIM * KD * 2;   // shared B2 slice
#pragma unroll
  for (int q = 0; q < 2; ++q) {
    int row = (wid * 2 + q) * 8 + rsub;                 // 0..63
    gA[q] = (const char*)A + (size_t)(i0 + row) * (KD * 2) + csw;
  }
#pragma unroll
  for (int q = 0; q < 4; ++q) {
    int row = (wid * 4 + q) * 8 + rsub;                 // 0..127
    gB[q] = Bg + (size_t)(ct * 128 + row) * (KD * 2) + csw;
  }

  f32x4 acc[4][2];
#pragma unroll
  for (int m2 = 0; m2 < 4; ++m2)
#pragma unroll
    for (int n2 = 0; n2 < 2; ++n2) acc[m2][n2] = f32x4{0.f, 0.f, 0.f, 0.f};

  int rA[4], rB[2], cS[2];
#pragma unroll
  for (int m2 = 0; m2 < 4; ++m2) rA[m2] = (m2 * 16 + (lane & 15)) * 64;
#pragma unroll
  for (int n2 = 0; n2 < 2; ++n2) rB[n2] = (wid * 32 + n2 * 16 + (lane & 15)) * 64;
#pragma unroll
  for (int kk = 0; kk < 2; ++kk) cS[kk] = ((kk * 4 + (lane >> 4)) ^ (lane & 7)) * 8;

  for (int k0 = 0; k0 < KD; k0 += 64) {
    size_t kb = (size_t)k0 * 2;
#pragma unroll
    for (int q = 0; q < 2; ++q)
      load_lds16(gA[q] + kb, &As[((wid * 2 + q) * 8) * 64]);
#pragma unroll
    for (int q = 0; q < 4; ++q)
      load_lds16(gB[q] + kb, &Bs[((wid * 4 + q) * 8) * 64]);
    __syncthreads();
#pragma unroll
    for (int kk = 0; kk < 2; ++kk) {
      bf16x8 af[4], bfr[2];
#pragma unroll
      for (int m2 = 0; m2 < 4; ++m2) af[m2] = *(const bf16x8*)&As[rA[m2] + cS[kk]];
#pragma unroll
      for (int n2 = 0; n2 < 2; ++n2) bfr[n2] = *(const bf16x8*)&Bs[rB[n2] + cS[kk]];
#pragma unroll
      for (int m2 = 0; m2 < 4; ++m2)
#pragma unroll
        for (int n2 = 0; n2 < 2; ++n2)
          acc[m2][n2] = __builtin_amdgcn_mfma_f32_16x16x32_bf16(af[m2], bfr[n2], acc[m2][n2], 0, 0, 0);
    }
    __syncthreads();
  }

#pragma unroll
  for (int m2 = 0; m2 < 4; ++m2) {
    int rb = m2 * 16 + ((lane >> 4) << 2);
#pragma unroll
    for (int n2 = 0; n2 < 2; ++n2) {
      int col = ct * 128 + wid * 32 + n2 * 16 + (lane & 15);
#pragma unroll
      for (int r = 0; r < 4; ++r)
        Yout[(size_t)(i0 + rb + r) * DDIM + col] = acc[m2][n2][r];
    }
  }
}

// ---------------- combine: y[t] += p0*E[slot0] + p1*E[slot1] ----------------
// One block per token; thread handles one float4 (col = tid*4). Memory-bound:
// 33MB y read + 33MB E gathered read + 33MB y write ~= 100MB.
__global__ __launch_bounds__(256) void combine_kernel(
    float* __restrict__ y, const __bf16* __restrict__ Eout,
    const int* __restrict__ islot, const float* __restrict__ scale_row) {
  int t = blockIdx.x, tid = threadIdx.x;
  int s0 = islot[t * 2], s1 = islot[t * 2 + 1];
  float4* yp = (float4*)(y + (size_t)t * DDIM) + tid;
  float4 a = *yp;
  if (s0 >= 0) {
    float sc = scale_row[s0];
    bf16x4 e = *((const bf16x4*)(Eout + (size_t)(s0 - NTOK) * DDIM) + tid);
    a.x += sc * (float)e[0]; a.y += sc * (float)e[1];
    a.z += sc * (float)e[2]; a.w += sc * (float)e[3];
  }
  if (s1 >= 0) {
    float sc = scale_row[s1];
    bf16x4 e = *((const bf16x4*)(Eout + (size_t)(s1 - NTOK) * DDIM) + tid);
    a.x += sc * (float)e[0]; a.y += sc * (float)e[1];
    a.z += sc * (float)e[2]; a.w += sc * (float)e[3];
  }
  *yp = a;
}

extern "C" void kernel_launch(void* const* d_in, const int* in_sizes, int n_in,
                              void* d_out, int out_size, void* d_ws, size_t ws_size,
                              hipStream_t stream) {
  const float* x      = (const float*)d_in[0];
  const float* rw     = (const float*)d_in[1];
  const float* wfc    = (const float*)d_in[2];
  const float* wproj  = (const float*)d_in[3];
  const float* wsfc   = (const float*)d_in[4];
  const float* wsproj = (const float*)d_in[5];
  float* y = (float*)d_out;

  char* ws = (char*)d_ws;
  size_t off = 0;
  auto alloc = [&](size_t bytes) {
    void* p = ws + off;
    off += (bytes + 1023) & ~(size_t)1023;
    return p;
  };
  __bf16* xbf      = (__bf16*)alloc((size_t)NTOK * DDIM * 2);          // 16 MB
  __bf16* B1       = (__bf16*)alloc((size_t)9 * HDIM * DDIM * 2);      // 26 MB [9][1408][1024]
  __bf16* B2       = (__bf16*)alloc((size_t)9 * DDIM * HDIM * 2);      // 26 MB [9][1024][1408]
  __bf16* H        = (__bf16*)alloc((size_t)NROWS * HDIM * 2);         // 81 MB
  __bf16* Eout     = (__bf16*)alloc((size_t)8 * CAP * DDIM * 2);       // 40 MB [8*2560][1024]
  int*    tok_row  = (int*)alloc((size_t)NROWS * 4);
  float*  scale_row= (float*)alloc((size_t)NROWS * 4);
  int*    islot    = (int*)alloc((size_t)NTOK * 2 * 4);
  int2*   e01      = (int2*)alloc((size_t)NTOK * 8);
  float2* p01      = (float2*)alloc((size_t)NTOK * 8);
  int*    counts   = (int*)alloc(1024);
  float*  psum_part= (float*)alloc(256 * 8 * 4);
  int*    fcnt_part= (int*)alloc(256 * 8 * 4);
  (void)ws_size; (void)out_size; (void)in_sizes; (void)n_in;

  tconv3_kernel<<<dim3(44, 22, 18), 256, 0, stream>>>(wfc, B1, wsfc, wproj, B2, wsproj);
  router_kernel<<<256, 256, 0, stream>>>(x, rw, xbf, e01, p01, tok_row, scale_row,
                                         psum_part, fcnt_part);
  dispatch_kernel<<<1, 256, 0, stream>>>(e01, p01, tok_row, scale_row, counts, islot,
                                         psum_part, fcnt_part, y + YN);
  // GEMM1: H = relu(gather(x) @ B1)^2 ; 2464 virtual tiles over 1024 persistent blocks
  gemm_kernel<1024, 1408, true, 1, 0, 2464><<<1024, 256, 0, stream>>>(
      xbf, B1, H, counts, tok_row);
  // GEMM2a (shared): y = H_shared @ B2s (plain store; 1024 blocks = exactly 1 round)
  gemm2s_kernel<<<1024, 256, 0, stream>>>(H, B2, y);
  // GEMM2b (experts): Eout[slot] = H_exp @ B2 (plain bf16 store, no atomics)
  // NOTE: A = H un-offset; kernel's rowbase = NTOK + g*CAP addresses the
  // expert region of H internally (R21 passed H+NTOK*HDIM -> double offset).
  gemm_kernel<1408, 1024, false, 4, 2, 1280><<<1024, 256, 0, stream>>>(
      H, B2, Eout, counts, tok_row);
  // combine: y[t] += p0*E[s0] + p1*E[s1] via inverse map
  combine_kernel<<<NTOK, 256, 0, stream>>>(y, Eout, islot, scale_row);
}